// Round 2
// baseline (331.269 us; speedup 1.0000x reference)
//
#include <hip/hip_runtime.h>
#include <math.h>

#define S 4096
#define D 512
#define H 8
#define DK 64
#define WIN 128

// ---------------------------------------------------------------------------
// GEMM: C[m][n] = sum_e A[m][e] * Wt[n][e] + bias[n]
// M=4096, N=512, K=512 fixed. BM=BN=128, BK=16, 256 threads, 8x8 micro-tile.
// ---------------------------------------------------------------------------
__device__ __forceinline__ void gemm_body(const float* __restrict__ A,
                                          const float* __restrict__ Wt,
                                          const float* __restrict__ bias,
                                          float* __restrict__ C)
{
    __shared__ float As[16][132];
    __shared__ float Bs[16][132];
    const int tid = threadIdx.x;
    const int m0 = blockIdx.x * 128;
    const int n0 = blockIdx.y * 128;

    const int lrow = tid >> 2;          // 0..63
    const int lcg  = (tid & 3) * 4;     // 0,4,8,12

    const int tm = (tid >> 4) * 8;      // 0..120
    const int tn = (tid & 15) * 8;      // 0..120

    float acc[8][8] = {};

    for (int kb = 0; kb < 512; kb += 16) {
        float4 av0 = *(const float4*)&A [(size_t)(m0 + lrow)      * 512 + kb + lcg];
        float4 av1 = *(const float4*)&A [(size_t)(m0 + lrow + 64) * 512 + kb + lcg];
        float4 bv0 = *(const float4*)&Wt[(size_t)(n0 + lrow)      * 512 + kb + lcg];
        float4 bv1 = *(const float4*)&Wt[(size_t)(n0 + lrow + 64) * 512 + kb + lcg];
        __syncthreads();
        As[lcg + 0][lrow] = av0.x; As[lcg + 1][lrow] = av0.y;
        As[lcg + 2][lrow] = av0.z; As[lcg + 3][lrow] = av0.w;
        As[lcg + 0][lrow + 64] = av1.x; As[lcg + 1][lrow + 64] = av1.y;
        As[lcg + 2][lrow + 64] = av1.z; As[lcg + 3][lrow + 64] = av1.w;
        Bs[lcg + 0][lrow] = bv0.x; Bs[lcg + 1][lrow] = bv0.y;
        Bs[lcg + 2][lrow] = bv0.z; Bs[lcg + 3][lrow] = bv0.w;
        Bs[lcg + 0][lrow + 64] = bv1.x; Bs[lcg + 1][lrow + 64] = bv1.y;
        Bs[lcg + 2][lrow + 64] = bv1.z; Bs[lcg + 3][lrow + 64] = bv1.w;
        __syncthreads();
        #pragma unroll
        for (int kk = 0; kk < 16; ++kk) {
            float a[8], b[8];
            *(float4*)&a[0] = *(const float4*)&As[kk][tm];
            *(float4*)&a[4] = *(const float4*)&As[kk][tm + 4];
            *(float4*)&b[0] = *(const float4*)&Bs[kk][tn];
            *(float4*)&b[4] = *(const float4*)&Bs[kk][tn + 4];
            #pragma unroll
            for (int i = 0; i < 8; ++i)
                #pragma unroll
                for (int j = 0; j < 8; ++j)
                    acc[i][j] = fmaf(a[i], b[j], acc[i][j]);
        }
    }

    #pragma unroll
    for (int i = 0; i < 8; ++i) {
        const size_t row = (size_t)(m0 + tm + i) * 512 + n0 + tn;
        float4 o0, o1;
        o0.x = acc[i][0] + bias[n0 + tn + 0];
        o0.y = acc[i][1] + bias[n0 + tn + 1];
        o0.z = acc[i][2] + bias[n0 + tn + 2];
        o0.w = acc[i][3] + bias[n0 + tn + 3];
        o1.x = acc[i][4] + bias[n0 + tn + 4];
        o1.y = acc[i][5] + bias[n0 + tn + 5];
        o1.z = acc[i][6] + bias[n0 + tn + 6];
        o1.w = acc[i][7] + bias[n0 + tn + 7];
        *(float4*)&C[row]     = o0;
        *(float4*)&C[row + 4] = o1;
    }
}

__global__ __launch_bounds__(256) void proj3_kernel(
    const float* __restrict__ x,
    const float* __restrict__ wq, const float* __restrict__ bq,
    const float* __restrict__ wk, const float* __restrict__ bk,
    const float* __restrict__ wv, const float* __restrict__ bv,
    float* __restrict__ q, float* __restrict__ k, float* __restrict__ v)
{
    const float* Wt; const float* b; float* C;
    if (blockIdx.z == 0)      { Wt = wq; b = bq; C = q; }
    else if (blockIdx.z == 1) { Wt = wk; b = bk; C = k; }
    else                      { Wt = wv; b = bv; C = v; }
    gemm_body(x, Wt, b, C);
}

__global__ __launch_bounds__(256) void outproj_kernel(
    const float* __restrict__ ctx,
    const float* __restrict__ wo, const float* __restrict__ bo,
    float* __restrict__ out)
{
    gemm_body(ctx, wo, bo, out);
}

// ---------------------------------------------------------------------------
// Fused band attention weights: scores -> softmax -> full-row write (zeros
// outside band). One block per (64-query block, head). attn is written
// EXACTLY ONCE, fully coalesced — no memset needed.
// ---------------------------------------------------------------------------
__global__ __launch_bounds__(256) void band_attn_kernel(
    const float* __restrict__ q, const float* __restrict__ k,
    float* __restrict__ attn)
{
    __shared__ float Qs[64][68];    // transposed: Qs[d][row]
    __shared__ float Ks[64][68];    // transposed: Ks[d][col]
    __shared__ float P[64][328];    // band scores, local window coords
    __shared__ float rinvs[64];

    const int tid = threadIdx.x;
    const int h  = blockIdx.y;
    const int q0 = blockIdx.x * 64;
    const int w0 = q0 - 128;        // local window start (global col of P[.][0])

    const int lr = tid >> 2;            // 0..63
    const int ld = (tid & 3) * 16;      // 0,16,32,48

    #pragma unroll
    for (int t = 0; t < 4; ++t) {
        float4 v4 = *(const float4*)&q[(size_t)(q0 + lr) * 512 + h * 64 + ld + t * 4];
        Qs[ld + t * 4 + 0][lr] = v4.x;
        Qs[ld + t * 4 + 1][lr] = v4.y;
        Qs[ld + t * 4 + 2][lr] = v4.z;
        Qs[ld + t * 4 + 3][lr] = v4.w;
    }

    const int rr = (tid & 15) * 4;     // query row group
    const int cc = (tid >> 4) * 4;     // key col group (within 64-col chunk)

    for (int ch = 0; ch < 5; ++ch) {
        const int c0 = w0 + ch * 64;
        if (c0 < 0 || c0 >= S) continue;   // block-uniform
        __syncthreads();
        #pragma unroll
        for (int t = 0; t < 4; ++t) {
            float4 v4 = *(const float4*)&k[(size_t)(c0 + lr) * 512 + h * 64 + ld + t * 4];
            Ks[ld + t * 4 + 0][lr] = v4.x;
            Ks[ld + t * 4 + 1][lr] = v4.y;
            Ks[ld + t * 4 + 2][lr] = v4.z;
            Ks[ld + t * 4 + 3][lr] = v4.w;
        }
        __syncthreads();

        float sc[4][4] = {};
        #pragma unroll 8
        for (int d = 0; d < 64; ++d) {
            float4 qv = *(const float4*)&Qs[d][rr];
            float4 kv = *(const float4*)&Ks[d][cc];
            const float qa[4] = {qv.x, qv.y, qv.z, qv.w};
            const float ka[4] = {kv.x, kv.y, kv.z, kv.w};
            #pragma unroll
            for (int i = 0; i < 4; ++i)
                #pragma unroll
                for (int j = 0; j < 4; ++j)
                    sc[i][j] = fmaf(qa[i], ka[j], sc[i][j]);
        }

        #pragma unroll
        for (int i = 0; i < 4; ++i) {
            float4 o = {sc[i][0] * 0.125f, sc[i][1] * 0.125f,
                        sc[i][2] * 0.125f, sc[i][3] * 0.125f};
            *(float4*)&P[rr + i][ch * 64 + cc] = o;
        }
    }
    __syncthreads();

    // ---- per-row softmax over band (4 lanes per row) ----
    {
        const int r  = tid >> 2;
        const int l2 = tid & 3;
        const int i  = q0 + r;
        const int lo = max(i - WIN, 0) - w0;
        const int hi = min(i + WIN, S - 1) - w0;

        float m = -1e30f;
        for (int c = lo + l2; c <= hi; c += 4) m = fmaxf(m, P[r][c]);
        m = fmaxf(m, __shfl_xor(m, 1));
        m = fmaxf(m, __shfl_xor(m, 2));

        float sum = 0.f;
        for (int c = lo + l2; c <= hi; c += 4) {
            float e = __expf(P[r][c] - m);
            P[r][c] = e;
            sum += e;
        }
        sum += __shfl_xor(sum, 1);
        sum += __shfl_xor(sum, 2);
        if (l2 == 0) rinvs[r] = 1.0f / sum;
    }
    __syncthreads();

    // ---- write full rows, coalesced: 4096 floats per row, zeros outside band
    float* rowbase = attn + (size_t)h * S * S;
    for (int r = 0; r < 64; ++r) {
        const int i = q0 + r;
        float* rowp = rowbase + (size_t)i * S;
        const int lo = max(i - WIN, 0) - w0;
        const int hi = min(i + WIN, S - 1) - w0;
        const float rv = rinvs[r];
        #pragma unroll
        for (int t = 0; t < 4; ++t) {
            const int c4 = (tid + t * 256) << 2;  // element column 0..4092
            const int lc = c4 - w0;               // local window coord
            float4 o;
            if (lc >= lo && lc + 3 <= hi) {
                float4 p = *(const float4*)&P[r][lc];
                o.x = p.x * rv; o.y = p.y * rv; o.z = p.z * rv; o.w = p.w * rv;
            } else if (lc + 3 < lo || lc > hi) {
                o = make_float4(0.f, 0.f, 0.f, 0.f);
            } else {
                o.x = (lc + 0 >= lo && lc + 0 <= hi) ? P[r][lc + 0] * rv : 0.f;
                o.y = (lc + 1 >= lo && lc + 1 <= hi) ? P[r][lc + 1] * rv : 0.f;
                o.z = (lc + 2 >= lo && lc + 2 <= hi) ? P[r][lc + 2] * rv : 0.f;
                o.w = (lc + 3 >= lo && lc + 3 <= hi) ? P[r][lc + 3] * rv : 0.f;
            }
            *(float4*)&rowp[c4] = o;
        }
    }
}

// ---------------------------------------------------------------------------
// PV: ctx[i][d] = sum_j attn[i][j] * V[j][d] over the band.
// ---------------------------------------------------------------------------
__global__ __launch_bounds__(256) void band_pv_kernel(
    const float* __restrict__ attn, const float* __restrict__ v,
    float* __restrict__ ctx)
{
    __shared__ float Ps[64][68];   // transposed: Ps[j][row]
    __shared__ float Vs[64][68];   // natural:    Vs[j][d]
    const int tid = threadIdx.x;
    const int h  = blockIdx.y;
    const int q0 = blockIdx.x * 64;

    const int lr = tid >> 2;
    const int lc = (tid & 3) * 16;
    const float* aptr = attn + (size_t)h * S * S;

    const int rr = (tid & 15) * 4;     // query rows
    const int dd = (tid >> 4) * 4;     // output dims

    float acc[4][4] = {};

    for (int ch = 0; ch < 5; ++ch) {
        const int c0 = q0 - 128 + ch * 64;
        if (c0 < 0 || c0 >= S) continue;
        __syncthreads();
        #pragma unroll
        for (int t = 0; t < 4; ++t) {
            float4 p4 = *(const float4*)&aptr[(size_t)(q0 + lr) * S + c0 + lc + t * 4];
            Ps[lc + t * 4 + 0][lr] = p4.x;
            Ps[lc + t * 4 + 1][lr] = p4.y;
            Ps[lc + t * 4 + 2][lr] = p4.z;
            Ps[lc + t * 4 + 3][lr] = p4.w;
            *(float4*)&Vs[lr][lc + t * 4] =
                *(const float4*)&v[(size_t)(c0 + lr) * 512 + h * 64 + lc + t * 4];
        }
        __syncthreads();

        #pragma unroll 8
        for (int j = 0; j < 64; ++j) {
            float4 pv = *(const float4*)&Ps[j][rr];
            float4 vv = *(const float4*)&Vs[j][dd];
            const float pa[4] = {pv.x, pv.y, pv.z, pv.w};
            const float va[4] = {vv.x, vv.y, vv.z, vv.w};
            #pragma unroll
            for (int i = 0; i < 4; ++i)
                #pragma unroll
                for (int d2 = 0; d2 < 4; ++d2)
                    acc[i][d2] = fmaf(pa[i], va[d2], acc[i][d2]);
        }
    }

    #pragma unroll
    for (int i = 0; i < 4; ++i) {
        float4 o = {acc[i][0], acc[i][1], acc[i][2], acc[i][3]};
        *(float4*)&ctx[(size_t)(q0 + rr + i) * 512 + h * 64 + dd] = o;
    }
}

// ---------------------------------------------------------------------------
extern "C" void kernel_launch(void* const* d_in, const int* in_sizes, int n_in,
                              void* d_out, int out_size, void* d_ws, size_t ws_size,
                              hipStream_t stream)
{
    (void)in_sizes; (void)n_in; (void)out_size; (void)ws_size;
    const float* x  = (const float*)d_in[0];
    const float* wq = (const float*)d_in[1];
    const float* bq = (const float*)d_in[2];
    const float* wk = (const float*)d_in[3];
    const float* bk = (const float*)d_in[4];
    const float* wv = (const float*)d_in[5];
    const float* bv = (const float*)d_in[6];
    const float* wo = (const float*)d_in[7];
    const float* bo = (const float*)d_in[8];

    float* out  = (float*)d_out;                       // (S, D)
    float* attn = out + (size_t)S * D;                 // (H, S, S)

    float* q   = (float*)d_ws;
    float* k   = q + (size_t)S * D;
    float* v   = k + (size_t)S * D;
    float* ctx = v + (size_t)S * D;

    proj3_kernel<<<dim3(32, 4, 3), 256, 0, stream>>>(x, wq, bq, wk, bk, wv, bv, q, k, v);
    band_attn_kernel<<<dim3(64, 8), 256, 0, stream>>>(q, k, attn);
    band_pv_kernel<<<dim3(64, 8), 256, 0, stream>>>(attn, v, ctx);
    outproj_kernel<<<dim3(32, 4), 256, 0, stream>>>(ctx, wo, bo, out);
}

// Round 3
// 208.373 us; speedup vs baseline: 1.5898x; 1.5898x over previous
//
#include <hip/hip_runtime.h>
#include <hip/hip_bf16.h>
#include <math.h>

#define S 4096
#define D 512
#define H 8
#define DK 64
#define WIN 128

typedef __attribute__((ext_vector_type(8))) short bf16x8;
typedef __attribute__((ext_vector_type(4))) float f32x4;

__device__ __forceinline__ unsigned short f2bf(float f) {
    __hip_bfloat16 h = __float2bfloat16(f);
    return *(unsigned short*)&h;
}

// ---------------------------------------------------------------------------
// fp32 -> bf16 conversion (x). 8 elems/thread.
// ---------------------------------------------------------------------------
__global__ __launch_bounds__(256) void conv_bf16_kernel(
    const float* __restrict__ in, unsigned short* __restrict__ out, int n)
{
    const int i = (blockIdx.x * 256 + threadIdx.x) * 8;
    if (i >= n) return;
    float4 a = *(const float4*)&in[i];
    float4 b = *(const float4*)&in[i + 4];
    ushort4 o0 = {f2bf(a.x), f2bf(a.y), f2bf(a.z), f2bf(a.w)};
    ushort4 o1 = {f2bf(b.x), f2bf(b.y), f2bf(b.z), f2bf(b.w)};
    *(ushort4*)&out[i]     = o0;
    *(ushort4*)&out[i + 4] = o1;
}

// ---------------------------------------------------------------------------
// MFMA GEMM: C[m][n] = sum_e A[m][e]*W[n][e] + bias[n]
// A: bf16 (M x 512). W: fp32 (512 x 512), converted to bf16 while staging the
// 64-row B tile (full K) into LDS. C: fp32 (or bf16 if CB != null).
// Block 256 thr = 4 waves, BM=128, BN=64; wave = 32x64 (2x4 16x16 frags).
// ---------------------------------------------------------------------------
__device__ __forceinline__ void mfma_gemm_body(
    const unsigned short* __restrict__ A,
    const float* __restrict__ W,
    const float* __restrict__ bias,
    float* __restrict__ C,
    unsigned short* __restrict__ CB)
{
    __shared__ unsigned short Bs[64][520];

    const int tid  = threadIdx.x;
    const int m0   = blockIdx.x * 128;
    const int n0   = blockIdx.y * 64;
    const int wv   = tid >> 6;          // wave 0..3
    const int lane = tid & 63;
    const int l16  = lane & 15;
    const int klo  = (lane >> 4) * 8;

    // ---- stage B tile: rows n0..n0+63 of W, all K, fp32->bf16 ----
    // chunk c: row = c>>6, kc = (c&63)*8 ; one wave covers one full row.
    #pragma unroll
    for (int it = 0; it < 16; ++it) {
        const int c   = tid + it * 256;
        const int row = c >> 6;
        const int kc  = (c & 63) * 8;
        const float* src = &W[(size_t)(n0 + row) * 512 + kc];
        float4 a = *(const float4*)&src[0];
        float4 b = *(const float4*)&src[4];
        ushort4 o0 = {f2bf(a.x), f2bf(a.y), f2bf(a.z), f2bf(a.w)};
        ushort4 o1 = {f2bf(b.x), f2bf(b.y), f2bf(b.z), f2bf(b.w)};
        *(ushort4*)&Bs[row][kc]     = o0;
        *(ushort4*)&Bs[row][kc + 4] = o1;
    }
    __syncthreads();

    const unsigned short* arow0 = &A[(size_t)(m0 + wv * 32 + l16) * 512 + klo];
    const unsigned short* arow1 = arow0 + 16 * 512;

    f32x4 acc[2][4];
    #pragma unroll
    for (int r = 0; r < 2; ++r)
        #pragma unroll
        for (int nf = 0; nf < 4; ++nf)
            acc[r][nf] = (f32x4){0.f, 0.f, 0.f, 0.f};

    #pragma unroll 4
    for (int kb = 0; kb < 512; kb += 32) {
        bf16x8 a0 = *(const bf16x8*)&arow0[kb];
        bf16x8 a1 = *(const bf16x8*)&arow1[kb];
        #pragma unroll
        for (int nf = 0; nf < 4; ++nf) {
            bf16x8 b = *(const bf16x8*)&Bs[nf * 16 + l16][kb + klo];
            acc[0][nf] = __builtin_amdgcn_mfma_f32_16x16x32_bf16(a0, b, acc[0][nf], 0, 0, 0);
            acc[1][nf] = __builtin_amdgcn_mfma_f32_16x16x32_bf16(a1, b, acc[1][nf], 0, 0, 0);
        }
    }

    // ---- epilogue: C[row=(lane>>4)*4+v][col=lane&15] per fragment ----
    const int r0 = (lane >> 4) * 4;
    #pragma unroll
    for (int r = 0; r < 2; ++r) {
        #pragma unroll
        for (int nf = 0; nf < 4; ++nf) {
            const int col = n0 + nf * 16 + l16;
            const float bb = bias[col];
            #pragma unroll
            for (int vv = 0; vv < 4; ++vv) {
                const int row = m0 + wv * 32 + r * 16 + r0 + vv;
                const float val = acc[r][nf][vv] + bb;
                if (C)  C [(size_t)row * 512 + col] = val;
                if (CB) CB[(size_t)row * 512 + col] = f2bf(val);
            }
        }
    }
}

__global__ __launch_bounds__(256) void proj3_kernel(
    const unsigned short* __restrict__ xb,
    const float* __restrict__ wq, const float* __restrict__ bq,
    const float* __restrict__ wk, const float* __restrict__ bk,
    const float* __restrict__ wv, const float* __restrict__ bv,
    float* __restrict__ q, float* __restrict__ k, float* __restrict__ v)
{
    const float* W; const float* b; float* C;
    if (blockIdx.z == 0)      { W = wq; b = bq; C = q; }
    else if (blockIdx.z == 1) { W = wk; b = bk; C = k; }
    else                      { W = wv; b = bv; C = v; }
    mfma_gemm_body(xb, W, b, C, nullptr);
}

__global__ __launch_bounds__(256) void outproj_kernel(
    const unsigned short* __restrict__ ctxb,
    const float* __restrict__ wo, const float* __restrict__ bo,
    float* __restrict__ out)
{
    mfma_gemm_body(ctxb, wo, bo, out, nullptr);
}

// ---------------------------------------------------------------------------
// Fused band attention weights: scores -> softmax -> full-row write (zeros
// outside band). One block per (64-query block, head). attn written once.
// ---------------------------------------------------------------------------
__global__ __launch_bounds__(256) void band_attn_kernel(
    const float* __restrict__ q, const float* __restrict__ k,
    float* __restrict__ attn)
{
    __shared__ float Qs[64][68];    // transposed: Qs[d][row]
    __shared__ float Ks[64][68];    // transposed: Ks[d][col]
    __shared__ float P[64][328];    // band scores, local window coords
    __shared__ float rinvs[64];

    const int tid = threadIdx.x;
    const int h  = blockIdx.y;
    const int q0 = blockIdx.x * 64;
    const int w0 = q0 - 128;

    const int lr = tid >> 2;
    const int ld = (tid & 3) * 16;

    #pragma unroll
    for (int t = 0; t < 4; ++t) {
        float4 v4 = *(const float4*)&q[(size_t)(q0 + lr) * 512 + h * 64 + ld + t * 4];
        Qs[ld + t * 4 + 0][lr] = v4.x;
        Qs[ld + t * 4 + 1][lr] = v4.y;
        Qs[ld + t * 4 + 2][lr] = v4.z;
        Qs[ld + t * 4 + 3][lr] = v4.w;
    }

    const int rr = (tid & 15) * 4;
    const int cc = (tid >> 4) * 4;

    for (int ch = 0; ch < 5; ++ch) {
        const int c0 = w0 + ch * 64;
        if (c0 < 0 || c0 >= S) continue;
        __syncthreads();
        #pragma unroll
        for (int t = 0; t < 4; ++t) {
            float4 v4 = *(const float4*)&k[(size_t)(c0 + lr) * 512 + h * 64 + ld + t * 4];
            Ks[ld + t * 4 + 0][lr] = v4.x;
            Ks[ld + t * 4 + 1][lr] = v4.y;
            Ks[ld + t * 4 + 2][lr] = v4.z;
            Ks[ld + t * 4 + 3][lr] = v4.w;
        }
        __syncthreads();

        float sc[4][4] = {};
        #pragma unroll 8
        for (int d = 0; d < 64; ++d) {
            float4 qv = *(const float4*)&Qs[d][rr];
            float4 kv = *(const float4*)&Ks[d][cc];
            const float qa[4] = {qv.x, qv.y, qv.z, qv.w};
            const float ka[4] = {kv.x, kv.y, kv.z, kv.w};
            #pragma unroll
            for (int i = 0; i < 4; ++i)
                #pragma unroll
                for (int j = 0; j < 4; ++j)
                    sc[i][j] = fmaf(qa[i], ka[j], sc[i][j]);
        }

        #pragma unroll
        for (int i = 0; i < 4; ++i) {
            float4 o = {sc[i][0] * 0.125f, sc[i][1] * 0.125f,
                        sc[i][2] * 0.125f, sc[i][3] * 0.125f};
            *(float4*)&P[rr + i][ch * 64 + cc] = o;
        }
    }
    __syncthreads();

    {
        const int r  = tid >> 2;
        const int l2 = tid & 3;
        const int i  = q0 + r;
        const int lo = max(i - WIN, 0) - w0;
        const int hi = min(i + WIN, S - 1) - w0;

        float m = -1e30f;
        for (int c = lo + l2; c <= hi; c += 4) m = fmaxf(m, P[r][c]);
        m = fmaxf(m, __shfl_xor(m, 1));
        m = fmaxf(m, __shfl_xor(m, 2));

        float sum = 0.f;
        for (int c = lo + l2; c <= hi; c += 4) {
            float e = __expf(P[r][c] - m);
            P[r][c] = e;
            sum += e;
        }
        sum += __shfl_xor(sum, 1);
        sum += __shfl_xor(sum, 2);
        if (l2 == 0) rinvs[r] = 1.0f / sum;
    }
    __syncthreads();

    float* rowbase = attn + (size_t)h * S * S;
    for (int r = 0; r < 64; ++r) {
        const int i = q0 + r;
        float* rowp = rowbase + (size_t)i * S;
        const int lo = max(i - WIN, 0) - w0;
        const int hi = min(i + WIN, S - 1) - w0;
        const float rv = rinvs[r];
        #pragma unroll
        for (int t = 0; t < 4; ++t) {
            const int c4 = (tid + t * 256) << 2;
            const int lc = c4 - w0;
            float4 o;
            if (lc >= lo && lc + 3 <= hi) {
                float4 p = *(const float4*)&P[r][lc];
                o.x = p.x * rv; o.y = p.y * rv; o.z = p.z * rv; o.w = p.w * rv;
            } else if (lc + 3 < lo || lc > hi) {
                o = make_float4(0.f, 0.f, 0.f, 0.f);
            } else {
                o.x = (lc + 0 >= lo && lc + 0 <= hi) ? P[r][lc + 0] * rv : 0.f;
                o.y = (lc + 1 >= lo && lc + 1 <= hi) ? P[r][lc + 1] * rv : 0.f;
                o.z = (lc + 2 >= lo && lc + 2 <= hi) ? P[r][lc + 2] * rv : 0.f;
                o.w = (lc + 3 >= lo && lc + 3 <= hi) ? P[r][lc + 3] * rv : 0.f;
            }
            *(float4*)&rowp[c4] = o;
        }
    }
}

// ---------------------------------------------------------------------------
// PV: ctx[i][d] = sum_j attn[i][j] * V[j][d] over the band. ctx out in bf16.
// ---------------------------------------------------------------------------
__global__ __launch_bounds__(256) void band_pv_kernel(
    const float* __restrict__ attn, const float* __restrict__ v,
    unsigned short* __restrict__ ctxb)
{
    __shared__ float Ps[64][68];   // transposed: Ps[j][row]
    __shared__ float Vs[64][68];   // natural:    Vs[j][d]
    const int tid = threadIdx.x;
    const int h  = blockIdx.y;
    const int q0 = blockIdx.x * 64;

    const int lr = tid >> 2;
    const int lc = (tid & 3) * 16;
    const float* aptr = attn + (size_t)h * S * S;

    const int rr = (tid & 15) * 4;
    const int dd = (tid >> 4) * 4;

    float acc[4][4] = {};

    for (int ch = 0; ch < 5; ++ch) {
        const int c0 = q0 - 128 + ch * 64;
        if (c0 < 0 || c0 >= S) continue;
        __syncthreads();
        #pragma unroll
        for (int t = 0; t < 4; ++t) {
            float4 p4 = *(const float4*)&aptr[(size_t)(q0 + lr) * S + c0 + lc + t * 4];
            Ps[lc + t * 4 + 0][lr] = p4.x;
            Ps[lc + t * 4 + 1][lr] = p4.y;
            Ps[lc + t * 4 + 2][lr] = p4.z;
            Ps[lc + t * 4 + 3][lr] = p4.w;
            *(float4*)&Vs[lr][lc + t * 4] =
                *(const float4*)&v[(size_t)(c0 + lr) * 512 + h * 64 + lc + t * 4];
        }
        __syncthreads();

        #pragma unroll 8
        for (int j = 0; j < 64; ++j) {
            float4 pv = *(const float4*)&Ps[j][rr];
            float4 vv = *(const float4*)&Vs[j][dd];
            const float pa[4] = {pv.x, pv.y, pv.z, pv.w};
            const float va[4] = {vv.x, vv.y, vv.z, vv.w};
            #pragma unroll
            for (int i = 0; i < 4; ++i)
                #pragma unroll
                for (int d2 = 0; d2 < 4; ++d2)
                    acc[i][d2] = fmaf(pa[i], va[d2], acc[i][d2]);
        }
    }

    #pragma unroll
    for (int i = 0; i < 4; ++i) {
        ushort4 o = {f2bf(acc[i][0]), f2bf(acc[i][1]),
                     f2bf(acc[i][2]), f2bf(acc[i][3])};
        *(ushort4*)&ctxb[(size_t)(q0 + rr + i) * 512 + h * 64 + dd] = o;
    }
}

// ---------------------------------------------------------------------------
extern "C" void kernel_launch(void* const* d_in, const int* in_sizes, int n_in,
                              void* d_out, int out_size, void* d_ws, size_t ws_size,
                              hipStream_t stream)
{
    (void)in_sizes; (void)n_in; (void)out_size; (void)ws_size;
    const float* x  = (const float*)d_in[0];
    const float* wq = (const float*)d_in[1];
    const float* bq = (const float*)d_in[2];
    const float* wk = (const float*)d_in[3];
    const float* bk = (const float*)d_in[4];
    const float* wv = (const float*)d_in[5];
    const float* bv = (const float*)d_in[6];
    const float* wo = (const float*)d_in[7];
    const float* bo = (const float*)d_in[8];

    float* out  = (float*)d_out;                       // (S, D)
    float* attn = out + (size_t)S * D;                 // (H, S, S)

    float* q = (float*)d_ws;                           // 8 MB each
    float* k = q + (size_t)S * D;
    float* v = k + (size_t)S * D;
    unsigned short* xb   = (unsigned short*)(v + (size_t)S * D);  // 4 MB
    unsigned short* ctxb = xb + (size_t)S * D;                    // 4 MB

    conv_bf16_kernel<<<(S * D) / (256 * 8), 256, 0, stream>>>(x, xb, S * D);
    proj3_kernel<<<dim3(32, 8, 3), 256, 0, stream>>>(xb, wq, bq, wk, bk, wv, bv, q, k, v);
    band_attn_kernel<<<dim3(64, 8), 256, 0, stream>>>(q, k, attn);
    band_pv_kernel<<<dim3(64, 8), 256, 0, stream>>>(attn, v, ctxb);
    outproj_kernel<<<dim3(32, 8), 256, 0, stream>>>(ctxb, wo, bo, out);
}